// Round 1
// baseline (597.009 us; speedup 1.0000x reference)
//
#include <hip/hip_runtime.h>
#include <math.h>

// Problem constants (match reference setup_inputs)
#define B_     16
#define HQ_    32
#define HKV_   8
#define G_     4      // HQ / HKV
#define D_     128
#define BS_    16
#define MAXB_  256
#define MAXKV_ 4096
#define NPART_ 16
#define PART_  (MAXKV_ / NPART_)   // 256 tokens per partition

// SCALE * log2(e): softmax done in base-2 (exp2f is the HW op v_exp_f32)
#define SL_ (0.08838834764831845f * 1.4426950408889634f)

// ---------------------------------------------------------------------------
// Kernel 1: write the newest token's k/v into the paged caches at slot_mapping
// (reference write_kv_cache semantics). B*HKV*D = 16384 elements each.
// ---------------------------------------------------------------------------
__global__ void write_kv(const float* __restrict__ k, const float* __restrict__ v,
                         float* __restrict__ kc, float* __restrict__ vc,
                         const int* __restrict__ slot_mapping) {
    int i = blockIdx.x * blockDim.x + threadIdx.x;   // < B*HKV*D = 16384
    int b = i >> 10;                                  // HKV*D = 1024
    int r = i & 1023;
    int slot = slot_mapping[b];
    size_t o = (size_t)slot * (HKV_ * D_) + r;
    kc[o] = k[i];
    vc[o] = v[i];
}

// ---------------------------------------------------------------------------
// Kernel 2: flash-decode partials. One wave (64 threads) per (partition, kh, b).
// Wave serves all G=4 query heads sharing this kv head -> K/V read exactly once.
// Lane holds d = {2*lane, 2*lane+1} of each K/V row (float2 -> 512B coalesced).
// ---------------------------------------------------------------------------
__launch_bounds__(64)
__global__ void attn_partial(const float* __restrict__ q,
                             const float* __restrict__ kc,
                             const float* __restrict__ vc,
                             const int* __restrict__ block_tables,
                             const int* __restrict__ seq_lens,
                             float* __restrict__ ws_acc,   // [B*HKV*G][NPART][D]
                             float* __restrict__ ws_ml) {  // [B*HKV*G][NPART][2]
    const int p    = blockIdx.x;
    const int kh   = blockIdx.y;
    const int b    = blockIdx.z;
    const int lane = threadIdx.x;

    const int seq_len = seq_lens[b];
    const int start   = p * PART_;
    if (start >= seq_len) return;              // combine kernel skips invalid p
    const int end = min(start + PART_, seq_len);

    // q fragments: 4 heads x float2 per lane, stays in registers
    float2 qv[G_];
#pragma unroll
    for (int g = 0; g < G_; ++g)
        qv[g] = *(const float2*)(q + (size_t)(b * HQ_ + kh * G_ + g) * D_ + 2 * lane);

    float m[G_], l[G_], ax[G_], ay[G_];
#pragma unroll
    for (int g = 0; g < G_; ++g) { m[g] = -1e30f; l[g] = 0.f; ax[g] = 0.f; ay[g] = 0.f; }

    const int* btr = block_tables + b * MAXB_;

    int s = start;
    // 2-token unroll: both K/V row loads issued before the dependent reduce,
    // and softmax rescale (alpha) amortized over the pair.
    for (; s + 1 < end; s += 2) {
        int blk0 = btr[s >> 4];
        int blk1 = btr[(s + 1) >> 4];
        size_t base0 = ((size_t)((blk0 << 4) | (s & 15)) * HKV_ + kh) * D_;
        size_t base1 = ((size_t)((blk1 << 4) | ((s + 1) & 15)) * HKV_ + kh) * D_;
        float2 k0 = *(const float2*)(kc + base0 + 2 * lane);
        float2 k1 = *(const float2*)(kc + base1 + 2 * lane);
        float2 v0 = *(const float2*)(vc + base0 + 2 * lane);
        float2 v1 = *(const float2*)(vc + base1 + 2 * lane);

        float sc0[G_], sc1[G_];
#pragma unroll
        for (int g = 0; g < G_; ++g) {
            sc0[g] = qv[g].x * k0.x + qv[g].y * k0.y;
            sc1[g] = qv[g].x * k1.x + qv[g].y * k1.y;
        }
#pragma unroll
        for (int off = 32; off >= 1; off >>= 1) {
#pragma unroll
            for (int g = 0; g < G_; ++g) {
                sc0[g] += __shfl_xor(sc0[g], off, 64);
                sc1[g] += __shfl_xor(sc1[g], off, 64);
            }
        }
#pragma unroll
        for (int g = 0; g < G_; ++g) {
            float s0 = sc0[g] * SL_;
            float s1 = sc1[g] * SL_;
            float mn = fmaxf(m[g], fmaxf(s0, s1));
            float alpha = exp2f(m[g] - mn);
            float p0 = exp2f(s0 - mn);
            float p1 = exp2f(s1 - mn);
            l[g]  = l[g]  * alpha + p0 + p1;
            ax[g] = ax[g] * alpha + p0 * v0.x + p1 * v1.x;
            ay[g] = ay[g] * alpha + p0 * v0.y + p1 * v1.y;
            m[g] = mn;
        }
    }
    // tail (odd token count)
    if (s < end) {
        int blk0 = btr[s >> 4];
        size_t base0 = ((size_t)((blk0 << 4) | (s & 15)) * HKV_ + kh) * D_;
        float2 k0 = *(const float2*)(kc + base0 + 2 * lane);
        float2 v0 = *(const float2*)(vc + base0 + 2 * lane);
        float sc0[G_];
#pragma unroll
        for (int g = 0; g < G_; ++g)
            sc0[g] = qv[g].x * k0.x + qv[g].y * k0.y;
#pragma unroll
        for (int off = 32; off >= 1; off >>= 1)
#pragma unroll
            for (int g = 0; g < G_; ++g)
                sc0[g] += __shfl_xor(sc0[g], off, 64);
#pragma unroll
        for (int g = 0; g < G_; ++g) {
            float s0 = sc0[g] * SL_;
            float mn = fmaxf(m[g], s0);
            float alpha = exp2f(m[g] - mn);
            float p0 = exp2f(s0 - mn);
            l[g]  = l[g]  * alpha + p0;
            ax[g] = ax[g] * alpha + p0 * v0.x;
            ay[g] = ay[g] * alpha + p0 * v0.y;
            m[g] = mn;
        }
    }

    // write partials: acc coalesced float2 per lane, lane0 writes (m,l)
#pragma unroll
    for (int g = 0; g < G_; ++g) {
        int hidx = (b * HKV_ + kh) * G_ + g;           // == b*HQ + kh*G+g
        float2 st; st.x = ax[g]; st.y = ay[g];
        *(float2*)(ws_acc + (size_t)(hidx * NPART_ + p) * D_ + 2 * lane) = st;
        if (lane == 0) {
            ws_ml[(size_t)(hidx * NPART_ + p) * 2 + 0] = m[g];
            ws_ml[(size_t)(hidx * NPART_ + p) * 2 + 1] = l[g];
        }
    }
}

// ---------------------------------------------------------------------------
// Kernel 3: combine partitions with log-sum-exp merge. One block per query head
// (B*HQ = 512 blocks), thread d handles output element d.
// ---------------------------------------------------------------------------
__launch_bounds__(128)
__global__ void attn_combine(const float* __restrict__ ws_acc,
                             const float* __restrict__ ws_ml,
                             const int* __restrict__ seq_lens,
                             float* __restrict__ out) {
    const int hidx = blockIdx.x;        // b*HQ + h
    const int d    = threadIdx.x;
    const int b    = hidx / HQ_;
    const int seq_len = seq_lens[b];
    const int nvalid  = min(NPART_, (seq_len + PART_ - 1) / PART_);

    float M = -1e30f, L = 0.f, o = 0.f;
    for (int p = 0; p < nvalid; ++p) {
        float mp = ws_ml[(size_t)(hidx * NPART_ + p) * 2 + 0];
        float lp = ws_ml[(size_t)(hidx * NPART_ + p) * 2 + 1];
        float a  = ws_acc[(size_t)(hidx * NPART_ + p) * D_ + d];
        float mn = fmaxf(M, mp);
        float so = exp2f(M - mn);
        float sn = exp2f(mp - mn);
        o = o * so + a * sn;
        L = L * so + lp * sn;
        M = mn;
    }
    out[(size_t)hidx * D_ + d] = o / L;
}

// ---------------------------------------------------------------------------
extern "C" void kernel_launch(void* const* d_in, const int* in_sizes, int n_in,
                              void* d_out, int out_size, void* d_ws, size_t ws_size,
                              hipStream_t stream) {
    const float* q  = (const float*)d_in[0];
    const float* k  = (const float*)d_in[1];
    const float* v  = (const float*)d_in[2];
    float* kc       = (float*)d_in[3];   // mutated; harness restores before each launch
    float* vc       = (float*)d_in[4];
    const int* slot = (const int*)d_in[5];
    const int* bt   = (const int*)d_in[6];
    const int* sl   = (const int*)d_in[7];
    float* out      = (float*)d_out;

    float* ws_acc = (float*)d_ws;                            // B*HQ*NPART*D floats = 4 MB
    float* ws_ml  = ws_acc + (size_t)B_ * HQ_ * NPART_ * D_; // + B*HQ*NPART*2 floats

    hipLaunchKernelGGL(write_kv, dim3((B_ * HKV_ * D_) / 256), dim3(256), 0, stream,
                       k, v, kc, vc, slot);
    hipLaunchKernelGGL(attn_partial, dim3(NPART_, HKV_, B_), dim3(64), 0, stream,
                       q, kc, vc, bt, sl, ws_acc, ws_ml);
    hipLaunchKernelGGL(attn_combine, dim3(B_ * HQ_), dim3(128), 0, stream,
                       ws_acc, ws_ml, sl, out);
}

// Round 2
// 493.785 us; speedup vs baseline: 1.2090x; 1.2090x over previous
//
#include <hip/hip_runtime.h>
#include <math.h>

// Problem constants (match reference setup_inputs)
#define B_     16
#define HQ_    32
#define HKV_   8
#define G_     4      // HQ / HKV
#define D_     128
#define BS_    16
#define MAXB_  256
#define MAXKV_ 4096

// SCALE * log2(e): softmax in base-2 (exp2f == v_exp_f32)
#define SL_ (0.08838834764831845f * 1.4426950408889634f)
#define NEGINF_ (-1e30f)

// ---------------------------------------------------------------------------
// Flash-decode partials. One wave per (partition, kh, b). The wave serves all
// G=4 query heads of this kv head -> K/V read exactly once from HBM.
//
// Half-wave token layout: lane = 32*half + l32. Each lane holds a float4
// d-slice (d = 4*l32 .. 4*l32+3). Lanes 0-31 process even tokens of a pair,
// lanes 32-63 odd tokens -> one 16B/lane wave-load covers TWO K rows (1 KB).
// Each half runs an independent online softmax; halves merged once at the end.
//
// The caches are NEVER written: the newest token (position seq_len-1) is
// attended directly from the fresh k/v inputs by the partition that owns it.
// ---------------------------------------------------------------------------
template<int NPART>
__launch_bounds__(64)
__global__ void attn_partial(const float* __restrict__ q,
                             const float* __restrict__ kin,
                             const float* __restrict__ vin,
                             const float* __restrict__ kc,
                             const float* __restrict__ vc,
                             const int* __restrict__ block_tables,
                             const int* __restrict__ seq_lens,
                             float* __restrict__ ws_acc,   // [B*HQ][NPART][D]
                             float* __restrict__ ws_ml) {  // [B*HQ][NPART][2]
    constexpr int PART = MAXKV_ / NPART;
    constexpr int NB   = PART / BS_;          // 16-token blocks per partition
    const int p    = blockIdx.x;
    const int kh   = blockIdx.y;
    const int b    = blockIdx.z;
    const int lane = threadIdx.x;
    const int half = lane >> 5;
    const int l32  = lane & 31;

    const int seq   = seq_lens[b];
    const int start = p * PART;
    if (start >= seq) return;                 // combine skips inactive partitions
    const int last    = seq - 1;              // newest token: read from kin/vin
    const int end_eff = min(start + PART, last); // cache-resident tokens only

    // q fragments: 4 heads x float4 per lane
    float4 qv[G_];
#pragma unroll
    for (int g = 0; g < G_; ++g)
        qv[g] = *(const float4*)(q + (size_t)(b * HQ_ + kh * G_ + g) * D_ + 4 * l32);

    float  m[G_], l_[G_];
    float4 acc[G_];
#pragma unroll
    for (int g = 0; g < G_; ++g) {
        m[g] = NEGINF_; l_[g] = 0.f;
        acc[g].x = acc[g].y = acc[g].z = acc[g].w = 0.f;
    }

    // preload this partition's block ids (contiguous, 16B-aligned)
    int blks[NB];
#pragma unroll
    for (int i = 0; i < NB; i += 4) {
        int4 t4 = *(const int4*)(block_tables + b * MAXB_ + (start >> 4) + i);
        blks[i] = t4.x; blks[i + 1] = t4.y; blks[i + 2] = t4.z; blks[i + 3] = t4.w;
    }

#pragma unroll
    for (int bi = 0; bi < NB; ++bi) {
        const int sb = start + bi * BS_;
        if (sb >= end_eff) break;             // wave-uniform
        const size_t rowbase = ((size_t)blks[bi] * (BS_ * HKV_) + kh) * D_ + 4 * l32;
        const float* kb = kc + rowbase;
        const float* vb = vc + rowbase;
#pragma unroll
        for (int ii = 0; ii < 2; ++ii) {
            const int t0 = sb + ii * 8;
            if (t0 >= end_eff) break;         // wave-uniform
            // 8 tokens: 4 pairs, each pair = one K + one V wave-load (1KB each)
            float4 kv[4], vv[4];
#pragma unroll
            for (int j = 0; j < 4; ++j) {
                const int off = ii * 8 + 2 * j + half;   // token slot in block
                kv[j] = *(const float4*)(kb + (size_t)off * (HKV_ * D_));
                vv[j] = *(const float4*)(vb + (size_t)off * (HKV_ * D_));
            }
#pragma unroll
            for (int j = 0; j < 4; ++j) {
                const int  t     = t0 + 2 * j + half;
                const bool valid = t < end_eff;
                float sc[G_];
#pragma unroll
                for (int g = 0; g < G_; ++g) {
                    float s = qv[g].x * kv[j].x;
                    s = fmaf(qv[g].y, kv[j].y, s);
                    s = fmaf(qv[g].z, kv[j].z, s);
                    sc[g] = fmaf(qv[g].w, kv[j].w, s);
                }
                // reduce within each 32-lane half (5 stages)
#pragma unroll
                for (int off = 16; off >= 1; off >>= 1)
#pragma unroll
                    for (int g = 0; g < G_; ++g)
                        sc[g] += __shfl_xor(sc[g], off, 64);
#pragma unroll
                for (int g = 0; g < G_; ++g) {
                    float s  = valid ? sc[g] * SL_ : NEGINF_;
                    float mn = fmaxf(m[g], s);
                    float al = exp2f(m[g] - mn);
                    float pp = exp2f(s - mn);
                    l_[g]    = l_[g] * al + pp;
                    acc[g].x = fmaf(acc[g].x, al, pp * vv[j].x);
                    acc[g].y = fmaf(acc[g].y, al, pp * vv[j].y);
                    acc[g].z = fmaf(acc[g].z, al, pp * vv[j].z);
                    acc[g].w = fmaf(acc[g].w, al, pp * vv[j].w);
                    m[g] = mn;
                }
            }
        }
    }

    // newest token from the fresh k/v inputs (only the owning partition)
    if (last - start < PART) {
        const float4 kf = *(const float4*)(kin + (size_t)(b * HKV_ + kh) * D_ + 4 * l32);
        const float4 vf = *(const float4*)(vin + (size_t)(b * HKV_ + kh) * D_ + 4 * l32);
        float sc[G_];
#pragma unroll
        for (int g = 0; g < G_; ++g) {
            float s = qv[g].x * kf.x;
            s = fmaf(qv[g].y, kf.y, s);
            s = fmaf(qv[g].z, kf.z, s);
            sc[g] = fmaf(qv[g].w, kf.w, s);
        }
#pragma unroll
        for (int off = 16; off >= 1; off >>= 1)
#pragma unroll
            for (int g = 0; g < G_; ++g)
                sc[g] += __shfl_xor(sc[g], off, 64);
#pragma unroll
        for (int g = 0; g < G_; ++g) {
            float s  = (half == 0) ? sc[g] * SL_ : NEGINF_;  // count token once
            float mn = fmaxf(m[g], s);
            float al = exp2f(m[g] - mn);
            float pp = exp2f(s - mn);
            l_[g]    = l_[g] * al + pp;
            acc[g].x = fmaf(acc[g].x, al, pp * vf.x);
            acc[g].y = fmaf(acc[g].y, al, pp * vf.y);
            acc[g].z = fmaf(acc[g].z, al, pp * vf.z);
            acc[g].w = fmaf(acc[g].w, al, pp * vf.w);
            m[g] = mn;
        }
    }

    // merge the two half-wave softmax states (all lanes compute; 0-31 store)
#pragma unroll
    for (int g = 0; g < G_; ++g) {
        float  mo = __shfl_xor(m[g], 32, 64);
        float  lo = __shfl_xor(l_[g], 32, 64);
        float4 ao;
        ao.x = __shfl_xor(acc[g].x, 32, 64);
        ao.y = __shfl_xor(acc[g].y, 32, 64);
        ao.z = __shfl_xor(acc[g].z, 32, 64);
        ao.w = __shfl_xor(acc[g].w, 32, 64);
        float mn = fmaxf(m[g], mo);
        float a  = exp2f(m[g] - mn);
        float c  = exp2f(mo  - mn);
        float lm = l_[g] * a + lo * c;
        float4 am;
        am.x = acc[g].x * a + ao.x * c;
        am.y = acc[g].y * a + ao.y * c;
        am.z = acc[g].z * a + ao.z * c;
        am.w = acc[g].w * a + ao.w * c;

        const int hidx = (b * HKV_ + kh) * G_ + g;   // == b*HQ + head
        if (half == 0) {
            *(float4*)(ws_acc + (size_t)(hidx * NPART + p) * D_ + 4 * l32) = am;
            if (l32 == 0) {
                ws_ml[(size_t)(hidx * NPART + p) * 2 + 0] = mn;
                ws_ml[(size_t)(hidx * NPART + p) * 2 + 1] = lm;
            }
        }
    }
}

// ---------------------------------------------------------------------------
// Combine partitions with log-sum-exp merge. One block per query head.
// ---------------------------------------------------------------------------
__launch_bounds__(128)
__global__ void attn_combine(const float* __restrict__ ws_acc,
                             const float* __restrict__ ws_ml,
                             const int* __restrict__ seq_lens,
                             float* __restrict__ out,
                             int npart, int part) {
    const int hidx = blockIdx.x;        // b*HQ + h
    const int d    = threadIdx.x;
    const int b    = hidx / HQ_;
    const int seq  = seq_lens[b];
    const int nvalid = min(npart, (seq + part - 1) / part);

    float M = NEGINF_, L = 0.f, o = 0.f;
    for (int p = 0; p < nvalid; ++p) {
        float mp = ws_ml[(size_t)(hidx * npart + p) * 2 + 0];
        float lp = ws_ml[(size_t)(hidx * npart + p) * 2 + 1];
        float a  = ws_acc[(size_t)(hidx * npart + p) * D_ + d];
        float mn = fmaxf(M, mp);
        float so = exp2f(M - mn);
        float sn = exp2f(mp - mn);
        o = o * so + a * sn;
        L = L * so + lp * sn;
        M = mn;
    }
    out[(size_t)hidx * D_ + d] = o / L;
}

// ---------------------------------------------------------------------------
template<int NPART>
static void launch_all(const float* q, const float* k, const float* v,
                       const float* kc, const float* vc,
                       const int* bt, const int* sl,
                       float* out, void* d_ws, hipStream_t stream) {
    float* ws_acc = (float*)d_ws;
    float* ws_ml  = ws_acc + (size_t)B_ * HQ_ * NPART * D_;
    hipLaunchKernelGGL((attn_partial<NPART>), dim3(NPART, HKV_, B_), dim3(64), 0, stream,
                       q, k, v, kc, vc, bt, sl, ws_acc, ws_ml);
    hipLaunchKernelGGL(attn_combine, dim3(B_ * HQ_), dim3(128), 0, stream,
                       ws_acc, ws_ml, sl, out, NPART, MAXKV_ / NPART);
}

extern "C" void kernel_launch(void* const* d_in, const int* in_sizes, int n_in,
                              void* d_out, int out_size, void* d_ws, size_t ws_size,
                              hipStream_t stream) {
    const float* q  = (const float*)d_in[0];
    const float* k  = (const float*)d_in[1];
    const float* v  = (const float*)d_in[2];
    const float* kc = (const float*)d_in[3];   // never mutated
    const float* vc = (const float*)d_in[4];
    // d_in[5] (slot_mapping) unused: newest token folded in from k/v directly
    const int* bt   = (const int*)d_in[6];
    const int* sl   = (const int*)d_in[7];
    float* out      = (float*)d_out;

    const size_t need64 = (size_t)B_ * HQ_ * 64 * (D_ + 2) * sizeof(float);
    const size_t need32 = (size_t)B_ * HQ_ * 32 * (D_ + 2) * sizeof(float);
    if (ws_size >= need64)      launch_all<64>(q, k, v, kc, vc, bt, sl, out, d_ws, stream);
    else if (ws_size >= need32) launch_all<32>(q, k, v, kc, vc, bt, sl, out, d_ws, stream);
    else                        launch_all<16>(q, k, v, kc, vc, bt, sl, out, d_ws, stream);
}